// Round 19
// baseline (770.906 us; speedup 1.0000x reference)
//
#include <hip/hip_runtime.h>
#include <hip/hip_bf16.h>

typedef unsigned short u16;
typedef __attribute__((ext_vector_type(8))) short short8;
typedef __attribute__((ext_vector_type(8))) unsigned short ushort8v;
typedef __attribute__((ext_vector_type(4))) float f32x4;

#define NPIX  65536
#define HH    256
#define WW    256
#define BATCH 2
#define CDIM  192
#define NHEADS 4
#define HD    48
#define OQKV  576
#define HIDN  510
#define OPAD  1024
#define NSLOT 32

// ---------- helpers ----------
__device__ __forceinline__ float bf2f(u16 b) {
  union { unsigned u; float f; } v; v.u = ((unsigned)b) << 16; return v.f;
}
__device__ __forceinline__ u16 f2bf(float f) {
  __bf16 h = (__bf16)f;
  u16 r; __builtin_memcpy(&r, &h, 2); return r;
}
__device__ __forceinline__ void atomAddF(float* p, float v) { unsafeAtomicAdd(p, v); }
__device__ __forceinline__ void gload16(const void* g, void* l) {
  __builtin_amdgcn_global_load_lds((const __attribute__((address_space(1))) unsigned int*)g,
                                   (__attribute__((address_space(3))) unsigned int*)l, 16, 0, 0);
}
// XCD-bijective swizzle (m204): blocks sharing data land on the same XCD's L2.
__device__ __forceinline__ void xcdswz(int& bx, int& by) {
  const int nx = gridDim.x;
  const int tot = nx * gridDim.y;
  const int lin = by * nx + bx;
  const int q = tot >> 3, r = tot & 7;
  const int xcd = lin & 7, pos = lin >> 3;
  const int nl = (xcd < r) ? (xcd * (q + 1) + pos) : (r * (q + 1) + (xcd - r) * q + pos);
  bx = nl % nx; by = nl / nx;
}
// 3-tap row conv on 8 consecutive px starting at col jm (row base rp). 1 vec + 2 scalar loads.
__device__ __forceinline__ void dw3row(const u16* __restrict__ rp, int jm, bool hasL, bool hasR,
                                       float w0, float w1, float w2, float* acc) {
  ushort8v m = *(const ushort8v*)(rp + jm);
  float f[10];
  f[0] = hasL ? bf2f(rp[jm - 1]) : 0.f;
  #pragma unroll
  for (int t = 0; t < 8; ++t) f[t + 1] = bf2f(m[t]);
  f[9] = hasR ? bf2f(rp[jm + 8]) : 0.f;
  #pragma unroll
  for (int i = 0; i < 8; ++i) acc[i] += w0 * f[i] + w1 * f[i + 1] + w2 * f[i + 2];
}

// ---------- ws layout (bytes) ----------
#define OFF_STATS1 ((size_t)0)                       // f32 [32][2][2] = 512
#define OFF_STATS2 ((size_t)512)                     // f32 [32][2][2] = 512
#define OFF_G      ((size_t)1024)                    // f32 [32][2][4][48][48] = 2,359,296
#define OFF_NQ     (OFF_G + 2359296)                 // f32 [32][2][4][48] = 49,152
#define OFF_NK     (OFF_NQ + 49152)                  // 49,152
#define ZERO_BYTES (OFF_NK + 49152)                  // 2,458,624 zeroed each launch
#define OFF_BQ     ZERO_BYTES                        // f32 [2][576] = 4608
#define OFF_B2     (OFF_BQ + 4608)                   // f32 [2][1024] = 8192
#define OFF_M      (OFF_B2 + 8192)                   // bf16 preswz [2][192][192] (reserve 294912)
#define OFF_WQ     (OFF_M + 294912)                  // bf16 [2][576][192] preswz
#define OFF_W2B    (OFF_WQ + 442368)                 // bf16 [2][1024][192] preswz
#define OFF_W3     (OFF_W2B + 786432)                // bf16 [192][512] preswz
#define OFF_T      (OFF_W3 + 196608)                 // bf16 xT [2][65536][192] (stays live)
#define OFF_QKV    (OFF_T + 50331648)                // bf16 planar qkv; q-slice->vdwT, k-slice->x2T
#define OFF_BAND   (OFF_QKV + 150994944)             // hpre band + ygT band

// ---------- 1. fused LN1 stats + transpose: f32 planar -> bf16 T preswz ----------
__global__ __launch_bounds__(256) void k_statsT(const float* __restrict__ P, u16* __restrict__ T,
                                                float* __restrict__ stats) {
  __shared__ u16 ld[128][200];
  const int b = blockIdx.y, n0 = blockIdx.x * 128, tid = threadIdx.x;
  const int slot = blockIdx.x & (NSLOT - 1);
  const float* Pb = P + (((size_t)b * CDIM) << 16) + n0;
  float s = 0.f, ss = 0.f;
  for (int it = 0; it < 24; ++it) {
    int idx = it * 256 + tid;           // 6144 float4: c(192) x j(32)
    int c = idx >> 5, j = idx & 31;
    float4 v = *(const float4*)(Pb + ((size_t)c << 16) + j * 4);
    s  += v.x + v.y + v.z + v.w;
    ss += v.x*v.x + v.y*v.y + v.z*v.z + v.w*v.w;
    int px = j * 4;
    ld[px][c] = f2bf(v.x); ld[px+1][c] = f2bf(v.y);
    ld[px+2][c] = f2bf(v.z); ld[px+3][c] = f2bf(v.w);
  }
  for (int off = 32; off; off >>= 1) { s += __shfl_down(s, off); ss += __shfl_down(ss, off); }
  __shared__ float ls[4], lss[4];
  const int wid = tid >> 6, lane = tid & 63;
  if (lane == 0) { ls[wid] = s; lss[wid] = ss; }
  __syncthreads();
  if (tid == 0) {
    atomAddF(&stats[(slot * BATCH + b) * 2 + 0], ls[0]+ls[1]+ls[2]+ls[3]);
    atomAddF(&stats[(slot * BATCH + b) * 2 + 1], lss[0]+lss[1]+lss[2]+lss[3]);
  }
  u16* Tb = T + (size_t)(b * NPIX + n0) * CDIM;
  for (int it = 0; it < 12; ++it) {
    int idx = it * 256 + tid;
    int ch = idx % 24, nl = idx / 24;
    union { u16 s[8]; uint4 v; } t;
    #pragma unroll
    for (int r = 0; r < 8; ++r) t.s[r] = ld[nl][ch * 8 + r];
    int sch = ch ^ (nl & 7);
    *(uint4*)((char*)(Tb + (size_t)nl * CDIM) + sch * 16) = t.v;
  }
}

// ---------- 2. fold LN into 1x1 weights -> bf16 preswz (key o&7) ----------
__global__ void k_fold(const float* __restrict__ w_in, const float* __restrict__ ln_w,
                       const float* __restrict__ ln_b, const float* __restrict__ stats,
                       u16* __restrict__ W, float* __restrict__ bias, int O_real) {
  const int o = blockIdx.x, b = blockIdx.y, c = threadIdx.x;
  const int Mtot = gridDim.x;
  const float n = (float)(CDIM * NPIX);
  float sum = 0.f, sumsq = 0.f;
  for (int sl = 0; sl < NSLOT; ++sl) {
    sum   += stats[(sl * BATCH + b) * 2 + 0];
    sumsq += stats[(sl * BATCH + b) * 2 + 1];
  }
  const float mean = sum / n;
  const float var = (sumsq - sum * sum / n) / (n - 1.f);
  const float inv = 1.f / (sqrtf(var) + 1e-6f);
  float we = 0.f, cb = 0.f;
  if (o < O_real) {
    float wi = w_in[o * CDIM + c];
    float a  = ln_w[c] * inv;
    we = wi * a;
    cb = wi * (ln_b[c] - mean * a);
  }
  int sch = (c >> 3) ^ (o & 7);
  W[((size_t)b * Mtot + o) * CDIM + sch * 8 + (c & 7)] = f2bf(we);
  for (int off = 32; off; off >>= 1) cb += __shfl_down(cb, off);
  __shared__ float l[3];
  if ((threadIdx.x & 63) == 0) l[threadIdx.x >> 6] = cb;
  __syncthreads();
  if (threadIdx.x == 0) bias[b * Mtot + o] = l[0] + l[1] + l[2];
}

// ---------- 2b. ff_out weights -> bf16 [192][512] preswz ----------
__global__ void k_fold3(const float* __restrict__ w, u16* __restrict__ W3) {
  const int o = blockIdx.x;
  for (int it = 0; it < 2; ++it) {
    int c = it * 256 + threadIdx.x;
    float v = (c < HIDN) ? w[o * HIDN + c] : 0.f;
    int sch = (c >> 3) ^ (o & 7);
    W3[o * 512 + sch * 8 + (c & 7)] = f2bf(v);
  }
}

// ---------- 4. MFMA GEMM: out[b,o,n] = sum_c A[b,o,c]*B[b,n,c] ----------
// KC multiple of 64 (XOR-swizzle closure). NT = n-tile (128 or 256; EPI!=0 requires 128).
// EPI=0: bf16 planar out + bias, stores staged via LDS -> uint4 (coalesced).
// EPI=2: x2 mode -- resid from swizzled bf16 rT, write ONLY swizzled bf16 tout; STATS opt.
// EPI=3: final mode -- resid from swizzled bf16 rT, f32 out staged via LDS -> float4.
template <int KTOT, int KC, int EPI, int STATS, int NT>
__global__ __launch_bounds__(256) void k_mgemm(
    const u16* __restrict__ Bm, const u16* __restrict__ Am,
    const float* __restrict__ bias,
    const u16* __restrict__ rT, long rTbstr,
    void* __restrict__ outv, long Obstr, int out_nstr,
    u16* __restrict__ tout, long toutbstr,
    int Mtot, long Bbstr, long Abstr,
    int nB_base, int nB_rows, int nO_base, float* __restrict__ stats)
{
  constexpr int RBC = KC * 2;
  constexpr int NFR = NT / 64;          // n-fragments per wave
  constexpr int LDSB = (NT + 64) * KC * 2;
  constexpr int EPIB = (EPI == 0) ? 64 * (NT + 8) * 2
                     : (EPI == 2) ? 128 * 66 * 4
                     : ((EPI == 3) ? 64 * 132 * 4 : 0);
  constexpr int TOT  = LDSB > EPIB ? LDSB : EPIB;
  __shared__ char lds[TOT];
  u16* lB = (u16*)lds;
  u16* lA = (u16*)(lds + NT * KC * 2);
  const int b = blockIdx.z;
  int bx = blockIdx.x, by = blockIdx.y;
  xcdswz(bx, by);
  const int o0 = bx * 64;
  const int nB = nB_base + by * NT;
  const int nO = nO_base + by * NT;
  const int tid = threadIdx.x;
  const int lane = tid & 63;
  const int wid = tid >> 6;

  if (EPI == 0 && (nB < 0 || nB >= nB_rows)) {
    u16* op = (u16*)outv;
    uint4 z; z.x = z.y = z.z = z.w = 0u;
    constexpr int CH8 = NT / 8;
    #pragma unroll
    for (int it = 0; it < NT / 32; ++it) {
      int idx = it * 256 + tid;
      int orow = idx / CH8, c8 = idx % CH8;
      *(uint4*)(op + (size_t)b * Obstr + (size_t)(o0 + orow) * out_nstr + nO + c8 * 8) = z;
    }
    return;
  }

  const u16* Bb = Bm + (size_t)b * Bbstr + (size_t)nB * KTOT;
  const u16* Ab = Am + (size_t)b * Abstr + (size_t)o0 * KTOT;

  f32x4 acc[4][NFR];
  #pragma unroll
  for (int m = 0; m < 4; ++m)
    #pragma unroll
    for (int nf = 0; nf < NFR; ++nf) acc[m][nf] = (f32x4){0.f, 0.f, 0.f, 0.f};

  for (int kc0 = 0; kc0 < KTOT; kc0 += KC) {
    if (kc0) __syncthreads();
    constexpr int NCH = KC / 8;
    #pragma unroll
    for (int it = 0; it < NT * NCH / 256; ++it) {
      int idx = it * 256 + tid; int r = idx / NCH, ch = idx % NCH;
      gload16((const char*)(Bb + (size_t)r * KTOT + kc0) + ch * 16, (char*)lB + idx * 16);
    }
    #pragma unroll
    for (int it = 0; it < 64 * NCH / 256; ++it) {
      int idx = it * 256 + tid; int r = idx / NCH, ch = idx % NCH;
      gload16((const char*)(Ab + (size_t)r * KTOT + kc0) + ch * 16, (char*)lA + idx * 16);
    }
    __syncthreads();
    const int lr = lane & 15, g = lane >> 4;
    #pragma unroll
    for (int ks = 0; ks < KC / 32; ++ks) {
      const int ck = ks * 4 + g;
      short8 afr[4], bfr[NFR];
      #pragma unroll
      for (int m = 0; m < 4; ++m) {
        int row = m * 16 + lr;
        afr[m] = *(const short8*)((const char*)lA + row * RBC + ((ck ^ (row & 7)) << 4));
      }
      #pragma unroll
      for (int nf = 0; nf < NFR; ++nf) {
        int row = wid * (NT / 4) + nf * 16 + lr;
        bfr[nf] = *(const short8*)((const char*)lB + row * RBC + ((ck ^ (row & 7)) << 4));
      }
      #pragma unroll
      for (int m = 0; m < 4; ++m)
        #pragma unroll
        for (int nf = 0; nf < NFR; ++nf)
          acc[m][nf] = __builtin_amdgcn_mfma_f32_16x16x32_bf16(afr[m], bfr[nf], acc[m][nf], 0, 0, 0);
    }
  }

  const int col = lane & 15, rg = lane >> 4;
  if constexpr (EPI == 0) {
    constexpr int NTP = NT + 8;
    u16* lst = (u16*)lds;
    __syncthreads();
    #pragma unroll
    for (int m = 0; m < 4; ++m)
      #pragma unroll
      for (int j = 0; j < 4; ++j) {
        int r = m * 16 + rg * 4 + j;
        float bv = bias[b * Mtot + o0 + r];
        #pragma unroll
        for (int nf = 0; nf < NFR; ++nf) {
          int nn = wid * (NT / 4) + nf * 16 + col;
          lst[r * NTP + nn] = f2bf(acc[m][nf][j] + bv);
        }
      }
    __syncthreads();
    u16* op = (u16*)outv;
    constexpr int CH8 = NT / 8;
    #pragma unroll
    for (int it = 0; it < 64 * CH8 / 256; ++it) {
      int idx = it * 256 + tid;
      int r = idx / CH8, ch = idx % CH8;
      uint4 v = *(const uint4*)(lst + r * NTP + ch * 8);
      *(uint4*)(op + (size_t)b * Obstr + (size_t)(o0 + r) * out_nstr + nO + ch * 8) = v;
    }
  } else if constexpr (EPI == 2) {
    // stage acc f32 into lds; then read swizzled rT, add, write swizzled tout only
    float* lBf = (float*)lds;
    __syncthreads();
    #pragma unroll
    for (int m = 0; m < 4; ++m)
      #pragma unroll
      for (int nf = 0; nf < NFR; ++nf)
        #pragma unroll
        for (int j = 0; j < 4; ++j)
          lBf[(wid * 32 + nf * 16 + col) * 66 + m * 16 + rg * 4 + j] = acc[m][nf][j];
    __syncthreads();
    float s = 0.f, ss = 0.f;
    for (int it = 0; it < 4; ++it) {
      int idx = it * 256 + tid;       // 1024 = 128 n x 8 chunks
      int n = idx >> 3, ch3 = idx & 7;
      size_t rowoff = (size_t)(nO + n) * CDIM;
      int chunk = (o0 >> 3) + (ch3 ^ (n & 7));
      uint4 xv = *(const uint4*)((const char*)(rT + (size_t)b * rTbstr + rowoff) + chunk * 16);
      u16* xs = (u16*)&xv;
      union { u16 s[8]; uint4 v; } t;
      #pragma unroll
      for (int r = 0; r < 8; ++r) {
        float rv = bf2f(xs[r]) + lBf[n * 66 + ch3 * 8 + r];
        t.s[r] = f2bf(rv);
        if constexpr (STATS) { s += rv; ss += rv * rv; }
      }
      *(uint4*)((char*)(tout + (size_t)b * toutbstr + rowoff) + chunk * 16) = t.v;
    }
    if constexpr (STATS) {
      for (int off = 32; off; off >>= 1) { s += __shfl_down(s, off); ss += __shfl_down(ss, off); }
      __shared__ float sr1[4], sr2[4];
      if (lane == 0) { sr1[wid] = s; sr2[wid] = ss; }
      __syncthreads();
      if (tid == 0) {
        int slot = by & (NSLOT - 1);
        atomAddF(&stats[(slot * BATCH + b) * 2 + 0], sr1[0]+sr1[1]+sr1[2]+sr1[3]);
        atomAddF(&stats[(slot * BATCH + b) * 2 + 1], sr2[0]+sr2[1]+sr2[2]+sr2[3]);
      }
    }
  } else {   // EPI == 3: add rT (x2T) into acc, stage f32 via LDS, write float4 planar
    u16* lAx = (u16*)lds;
    __syncthreads();
    for (int it = 0; it < 4; ++it) {
      int idx = it * 256 + tid;
      int n = idx >> 3, ch3 = idx & 7;
      int chunk = (o0 >> 3) + (ch3 ^ (n & 7));
      uint4 xv = *(const uint4*)((const char*)(rT + (size_t)b * rTbstr + (size_t)(nO + n) * CDIM) + chunk * 16);
      u16* xs = (u16*)&xv;
      #pragma unroll
      for (int r = 0; r < 8; ++r) lAx[n * 66 + ch3 * 8 + r] = xs[r];
    }
    __syncthreads();
    #pragma unroll
    for (int m = 0; m < 4; ++m)
      #pragma unroll
      for (int nf = 0; nf < NFR; ++nf)
        #pragma unroll
        for (int j = 0; j < 4; ++j) {
          int nl = wid * 32 + nf * 16 + col;
          acc[m][nf][j] += bf2f(lAx[nl * 66 + m * 16 + rg * 4 + j]);
        }
    __syncthreads();
    float* lstf = (float*)lds;
    #pragma unroll
    for (int m = 0; m < 4; ++m)
      #pragma unroll
      for (int nf = 0; nf < NFR; ++nf)
        #pragma unroll
        for (int j = 0; j < 4; ++j)
          lstf[(m * 16 + rg * 4 + j) * 132 + wid * 32 + nf * 16 + col] = acc[m][nf][j];
    __syncthreads();
    float* of = (float*)outv;
    #pragma unroll
    for (int it = 0; it < 8; ++it) {
      int idx = it * 256 + tid;       // 2048 = 64 o x 32 float4
      int r = idx >> 5, q4 = idx & 31;
      float4 v = *(const float4*)&lstf[r * 132 + q4 * 4];
      *(float4*)(of + (size_t)b * Obstr + (size_t)(o0 + r) * out_nstr + nO + q4 * 4) = v;
    }
  }
}

// ---------- 5. fused dw + Gram(MFMA) + L2 norms, 128-px half-row per block ----------
// Stride-128 LDS with XOR chunk swizzle (write j^(c&7), read ck^(row&7)).
__global__ __launch_bounds__(256) void k_gram(const u16* __restrict__ qkv,
                                              const float* __restrict__ dww,
                                              float* __restrict__ G,
                                              float* __restrict__ nq,
                                              float* __restrict__ nk) {
  __shared__ u16 qs[HD][128], ks2[HD][128];
  __shared__ u16 wq[HD][9], wk[HD][9];
  __shared__ float nql[HD], nkl[HD];
  int bx = blockIdx.x, by = blockIdx.y;
  xcdswz(bx, by);
  const int b = by >> 2, h = by & 3;
  const int row = bx >> 1, col0 = (bx & 1) * 128;
  const int slot = bx & (NSLOT - 1);
  const int bh = b * NHEADS + h;
  const int tid = threadIdx.x;

  for (int idx = tid; idx < HD * 9; idx += 256) {
    int c = idx / 9, k9 = idx % 9;
    wq[c][k9] = f2bf(dww[(h * HD + c) * 9 + k9]);
    wk[c][k9] = f2bf(dww[(CDIM + h * HD + c) * 9 + k9]);
  }
  __syncthreads();

  // phase 1: 1536 items = j(16) x c(48) x qk(2); each item: 8 px dw conv
  #pragma unroll 2
  for (int it = 0; it < 6; ++it) {
    int idx = it * 256 + tid;
    int j = idx & 15, cz = idx >> 4;
    int c = cz % HD, qk = cz / HD;
    const u16* base = qkv + (((size_t)(b * OQKV + qk * CDIM + h * HD + c)) << 16);
    const u16* w = qk ? wk[c] : wq[c];
    float acc[8] = {0.f,0.f,0.f,0.f,0.f,0.f,0.f,0.f};
    const int jm = col0 + j * 8;
    const bool hasL = jm > 0, hasR = jm < 248;
    if (row > 0)   dw3row(base + (row - 1) * 256, jm, hasL, hasR, bf2f(w[0]), bf2f(w[1]), bf2f(w[2]), acc);
                   dw3row(base + row * 256,       jm, hasL, hasR, bf2f(w[3]), bf2f(w[4]), bf2f(w[5]), acc);
    if (row < 255) dw3row(base + (row + 1) * 256, jm, hasL, hasR, bf2f(w[6]), bf2f(w[7]), bf2f(w[8]), acc);
    union { u16 s[8]; ushort8v v; } rv;
    float sqs = 0.f;
    #pragma unroll
    for (int i = 0; i < 8; ++i) {
      rv.s[i] = f2bf(acc[i]);
      sqs += acc[i] * acc[i];
    }
    const int sw = (j ^ (c & 7)) * 8;
    if (qk) *(ushort8v*)&ks2[c][sw] = rv.v;
    else    *(ushort8v*)&qs[c][sw]  = rv.v;
    // 16-lane group reduce: all lanes in a group share (c,qk); each (c,qk) occurs once
    sqs += __shfl_down(sqs, 8);
    sqs += __shfl_down(sqs, 4);
    sqs += __shfl_down(sqs, 2);
    sqs += __shfl_down(sqs, 1);
    if ((tid & 15) == 0) { if (qk) nkl[c] = sqs; else nql[c] = sqs; }
  }
  __syncthreads();

  if (tid < HD) atomAddF(&nq[(slot * 2 * NHEADS + bh) * HD + tid], nql[tid]);
  else if (tid < 2*HD) atomAddF(&nk[(slot * 2 * NHEADS + bh) * HD + tid - HD], nkl[tid - HD]);

  // phase 2: Gram via MFMA over 128 px; 9 fragment tiles over 4 waves
  const int lane = tid & 63, wid = tid >> 6;
  const int lr = lane & 15, g = lane >> 4;
  float* Gb = G + (size_t)(slot * 2 * NHEADS + bh) * HD * HD;
  for (int t = wid; t < 9; t += 4) {
    const int m = t / 3, nb = t % 3;
    f32x4 a4 = (f32x4){0.f, 0.f, 0.f, 0.f};
    #pragma unroll
    for (int ksi = 0; ksi < 4; ++ksi) {
      int ck = ksi * 4 + g;
      int ra = m * 16 + lr, rb = nb * 16 + lr;
      short8 af = *(const short8*)&qs[ra][(ck ^ (ra & 7)) * 8];
      short8 bf = *(const short8*)&ks2[rb][(ck ^ (rb & 7)) * 8];
      a4 = __builtin_amdgcn_mfma_f32_16x16x32_bf16(af, bf, a4, 0, 0, 0);
    }
    #pragma unroll
    for (int jj = 0; jj < 4; ++jj)
      atomAddF(&Gb[(m * 16 + g * 4 + jj) * HD + nb * 16 + lr], a4[jj]);
  }
}

// ---------- 6. reduce slot copies, normalize, softmax, proj -> M bf16 preswz ----------
__global__ void k_attnM(const float* __restrict__ G, const float* __restrict__ nq,
                        const float* __restrict__ nk, const float* __restrict__ temp,
                        const float* __restrict__ proj_w, u16* __restrict__ Mb16) {
  const int h = blockIdx.x, b = blockIdx.y;
  const int bh = b * NHEADS + h;
  __shared__ float at[HD][HD];
  __shared__ float nqs[HD], nks[HD];
  const int tid = threadIdx.x;
  if (tid < HD) {
    float s = 0.f;
    for (int sl = 0; sl < NSLOT; ++sl) s += nq[(sl * 2 * NHEADS + bh) * HD + tid];
    nqs[tid] = fmaxf(sqrtf(s), 1e-12f);
  } else if (tid >= 64 && tid < 64 + HD) {
    int c = tid - 64;
    float s = 0.f;
    for (int sl = 0; sl < NSLOT; ++sl) s += nk[(sl * 2 * NHEADS + bh) * HD + c];
    nks[c] = fmaxf(sqrtf(s), 1e-12f);
  }
  __syncthreads();
  const float t = temp[h];
  for (int idx = tid; idx < HD * HD; idx += 256) {
    int c = idx / HD, d = idx % HD;
    float g = 0.f;
    for (int sl = 0; sl < NSLOT; ++sl)
      g += G[(size_t)(sl * 2 * NHEADS + bh) * HD * HD + idx];
    at[c][d] = g / (nqs[c] * nks[d]) * t;
  }
  __syncthreads();
  if (tid < HD) {
    float m = -1e30f;
    for (int d = 0; d < HD; ++d) m = fmaxf(m, at[tid][d]);
    float s = 0.f;
    for (int d = 0; d < HD; ++d) { float e = __expf(at[tid][d] - m); at[tid][d] = e; s += e; }
    float inv = 1.f / s;
    for (int d = 0; d < HD; ++d) at[tid][d] *= inv;
  }
  __syncthreads();
  for (int idx = tid; idx < CDIM * HD; idx += 256) {
    int o = idx / HD, d = idx % HD;
    float acc = 0.f;
    for (int c = 0; c < HD; ++c) acc += proj_w[o * CDIM + h * HD + c] * at[c][d];
    int cf = h * HD + d;
    int sch = (cf >> 3) ^ (o & 7);
    Mb16[((size_t)(b * CDIM + o)) * CDIM + sch * 8 + (cf & 7)] = f2bf(acc);
  }
}

// ---------- 7. dw conv on V -> transposed preswz bf16 (into q-slice of qkv) ----------
__global__ __launch_bounds__(256) void k_dwT(const u16* __restrict__ qkv,
                                             const float* __restrict__ dww,
                                             u16* __restrict__ vdwT, long vdwbstr) {
  __shared__ u16 ld[64][201];
  __shared__ float w9[CDIM][9];
  int bx = blockIdx.x, by = blockIdx.y;
  xcdswz(bx, by);
  const int b = by;
  const int p0 = bx * 64;
  const int row = p0 >> 8, col0 = p0 & 255;
  const int tid = threadIdx.x;
  for (int idx = tid; idx < CDIM * 9; idx += 256) w9[idx / 9][idx % 9] = dww[384 * 9 + idx];
  __syncthreads();
  #pragma unroll 2
  for (int it = 0; it < 6; ++it) {
    int idx = it * 256 + tid;          // 1536 items: j(8) x c(192)
    int j = idx & 7, c = idx >> 3;
    const u16* base = qkv + (((size_t)(b * OQKV + 384 + c)) << 16);
    const float* w = w9[c];
    float acc[8] = {0.f,0.f,0.f,0.f,0.f,0.f,0.f,0.f};
    const int jm = col0 + j * 8;
    const bool hasL = jm > 0, hasR = jm < 248;
    if (row > 0)   dw3row(base + (row - 1) * 256, jm, hasL, hasR, w[0], w[1], w[2], acc);
                   dw3row(base + row * 256,       jm, hasL, hasR, w[3], w[4], w[5], acc);
    if (row < 255) dw3row(base + (row + 1) * 256, jm, hasL, hasR, w[6], w[7], w[8], acc);
    #pragma unroll
    for (int i = 0; i < 8; ++i) ld[j * 8 + i][c] = f2bf(acc[i]);
  }
  __syncthreads();
  u16* Tb = vdwT + (size_t)b * vdwbstr + (size_t)p0 * CDIM;
  for (int it = 0; it < 6; ++it) {
    int idx = it * 256 + tid;          // 1536 = 64 px * 24 chunks
    int ch = idx % 24, pl = idx / 24;
    union { u16 s[8]; uint4 v; } t;
    #pragma unroll
    for (int r = 0; r < 8; ++r) t.s[r] = ld[pl][ch * 8 + r];
    int sch = ch ^ (pl & 7);
    *(uint4*)((char*)(Tb + (size_t)pl * CDIM) + sch * 16) = t.v;
  }
}

// ---------- 8. dw + gelu gate on hpre band -> ygT (1 row, 32 cols per block) ----------
__global__ __launch_bounds__(256) void k_dwgT(const u16* __restrict__ hp_, const float* __restrict__ w9,
                                              u16* __restrict__ ygT, int rows_loc, int band_px) {
  __shared__ u16 ld[32][515];
  int bx = blockIdx.x, by = blockIdx.y;
  xcdswz(bx, by);
  const int b = by;
  const int p0 = bx * 32;
  const int olr = p0 >> 8, col0 = p0 & 255;
  const int tid = threadIdx.x;
  if (tid < 64) {                      // zero pad channels 510,511
    int px = tid >> 1, c = 510 + (tid & 1);
    ld[px][c] = 0;
  }
  __syncthreads();
  #pragma unroll 2
  for (int it = 0; it < 8; ++it) {
    int idx = it * 256 + tid;          // 2040 items: j(4) x c(510)
    if (idx < HIDN * 4) {
      int j = idx & 3, c = idx >> 2;
      const u16* ia = hp_ + (size_t)(b * OPAD + c) * rows_loc * 256;
      const u16* ig = hp_ + (size_t)(b * OPAD + c + HIDN) * rows_loc * 256;
      float aa[8] = {0.f,0.f,0.f,0.f,0.f,0.f,0.f,0.f};
      float gg[8] = {0.f,0.f,0.f,0.f,0.f,0.f,0.f,0.f};
      const int jm = col0 + j * 8;
      const bool hasL = jm > 0, hasR = jm < 248;
      #pragma unroll
      for (int dr = 0; dr < 3; ++dr) {
        dw3row(ia + (olr + dr) * 256, jm, hasL, hasR,
               w9[c * 9 + dr * 3], w9[c * 9 + dr * 3 + 1], w9[c * 9 + dr * 3 + 2], aa);
        dw3row(ig + (olr + dr) * 256, jm, hasL, hasR,
               w9[(c + HIDN) * 9 + dr * 3], w9[(c + HIDN) * 9 + dr * 3 + 1],
               w9[(c + HIDN) * 9 + dr * 3 + 2], gg);
      }
      #pragma unroll
      for (int i = 0; i < 8; ++i) {
        float a = aa[i];
        float gel = 0.5f * a * (1.f + erff(a * 0.70710678118654752f));
        ld[j * 8 + i][c] = f2bf(gel * gg[i]);
      }
    }
  }
  __syncthreads();
  u16* Tb = ygT + ((size_t)b * band_px + p0) * 512;
  for (int it = 0; it < 8; ++it) {
    int idx = it * 256 + tid;          // 2048 = 32 px * 64 chunks
    int ch = idx & 63, pl = idx >> 6;
    union { u16 s[8]; uint4 v; } t;
    #pragma unroll
    for (int r = 0; r < 8; ++r) t.s[r] = ld[pl][ch * 8 + r];
    int sch = ch ^ (pl & 7);
    *(uint4*)((char*)(Tb + (size_t)pl * 512) + sch * 16) = t.v;
  }
}

// ---------- launch ----------
extern "C" void kernel_launch(void* const* d_in, const int* in_sizes, int n_in,
                              void* d_out, int out_size, void* d_ws, size_t ws_size,
                              hipStream_t stream) {
  const float* x       = (const float*)d_in[0];
  const float* n1_w    = (const float*)d_in[1];
  const float* n1_b    = (const float*)d_in[2];
  const float* qkv_w   = (const float*)d_in[3];
  const float* qkv_dw  = (const float*)d_in[4];
  const float* proj_w  = (const float*)d_in[5];
  const float* temp    = (const float*)d_in[6];
  const float* n2_w    = (const float*)d_in[7];
  const float* n2_b    = (const float*)d_in[8];
  const float* ff_in_w = (const float*)d_in[9];
  const float* ff_dw   = (const float*)d_in[10];
  const float* ff_out_w= (const float*)d_in[11];

  char* ws = (char*)d_ws;
  float* stats1 = (float*)(ws + OFF_STATS1);
  float* stats2 = (float*)(ws + OFF_STATS2);
  float* G      = (float*)(ws + OFF_G);
  float* nq     = (float*)(ws + OFF_NQ);
  float* nk     = (float*)(ws + OFF_NK);
  float* biasq  = (float*)(ws + OFF_BQ);
  float* bias2  = (float*)(ws + OFF_B2);
  u16*   Mb16   = (u16*)(ws + OFF_M);
  u16*   Wq     = (u16*)(ws + OFF_WQ);
  u16*   W2b    = (u16*)(ws + OFF_W2B);
  u16*   W3     = (u16*)(ws + OFF_W3);
  u16*   xT     = (u16*)(ws + OFF_T);              // stays live through x2 gemm
  u16*   qkv    = (u16*)(ws + OFF_QKV);            // planar qkv
  u16*   vdwT   = qkv;                             // overlays dead q-slice
  u16*   x2T    = qkv + (size_t)CDIM * NPIX;       // overlays dead k-slice
  const long qkvbstr = (long)OQKV * NPIX;          // batch stride for both overlays
  float* outp   = (float*)d_out;

  int NP = 32;
  const int cand[5] = {1, 2, 4, 8, 16};
  for (int i = 0; i < 5; ++i) {
    int rws = 256 / cand[i], rl = rws + 2;
    size_t band = (size_t)2 * OPAD * rl * 256 * 2 + (size_t)2 * rws * 256 * 512 * 2;
    if (OFF_BAND + band + ((size_t)8 << 20) <= ws_size) { NP = cand[i]; break; }
  }
  const int rows = 256 / NP, rows_loc = rows + 2, band_px = rows * 256;
  u16* hpre = (u16*)(ws + OFF_BAND);
  u16* ygT  = (u16*)(ws + OFF_BAND + (size_t)2 * OPAD * rows_loc * 256 * 2);

  hipMemsetAsync(ws, 0, ZERO_BYTES, stream);

  // ---- attention ----
  k_statsT<<<dim3(NPIX / 128, BATCH), 256, 0, stream>>>(x, xT, stats1);
  k_fold<<<dim3(OQKV, BATCH), CDIM, 0, stream>>>(qkv_w, n1_w, n1_b, stats1, Wq, biasq, OQKV);
  k_mgemm<192, 64, 0, 0, 256><<<dim3(OQKV / 64, NPIX / 256, BATCH), 256, 0, stream>>>(
      xT, Wq, biasq, nullptr, 0L, qkv, (long)OQKV * NPIX, NPIX, nullptr, 0L,
      OQKV, (long)NPIX * CDIM, (long)OQKV * CDIM, 0, NPIX, 0, nullptr);
  k_gram<<<dim3(512, BATCH * NHEADS), 256, 0, stream>>>(qkv, qkv_dw, G, nq, nk);
  k_attnM<<<dim3(NHEADS, BATCH), 256, 0, stream>>>(G, nq, nk, temp, proj_w, Mb16);
  k_dwT<<<dim3(NPIX / 64, BATCH), 256, 0, stream>>>(qkv, qkv_dw, vdwT, qkvbstr);
  // x2 = x + M@dw(V): resid from xT (bf16 swz), write ONLY x2T (bf16 swz) + stats2
  k_mgemm<192, 64, 2, 1, 128><<<dim3(CDIM / 64, NPIX / 128, BATCH), 256, 0, stream>>>(
      vdwT, Mb16, nullptr, xT, (long)NPIX * CDIM, nullptr, 0L, 0, x2T, qkvbstr,
      CDIM, qkvbstr, (long)CDIM * CDIM, 0, NPIX, 0, stats2);

  // ---- GDFN ----
  k_fold<<<dim3(OPAD, BATCH), CDIM, 0, stream>>>(ff_in_w, n2_w, n2_b, stats2, W2b, bias2, 1020);
  k_fold3<<<dim3(CDIM), 256, 0, stream>>>(ff_out_w, W3);
  for (int rp = 0; rp < NP; ++rp) {
    const int band0 = rp * band_px;
    k_mgemm<192, 64, 0, 0, 256><<<dim3(OPAD / 64, rows_loc, BATCH), 256, 0, stream>>>(
        x2T, W2b, bias2, nullptr, 0L, hpre, (long)OPAD * rows_loc * 256, rows_loc * 256,
        nullptr, 0L, OPAD, qkvbstr, (long)OPAD * CDIM, band0 - 256, NPIX, 0, nullptr);
    k_dwgT<<<dim3(band_px / 32, BATCH), 256, 0, stream>>>(hpre, ff_dw, ygT, rows_loc, band_px);
    // out = x2 + ff_out@ygT: resid from x2T, f32 out staged -> float4
    k_mgemm<512, 128, 3, 0, 128><<<dim3(CDIM / 64, rows * 2, BATCH), 256, 0, stream>>>(
        ygT, W3, nullptr, x2T, qkvbstr, outp, (long)CDIM * NPIX, NPIX, nullptr, 0L,
        CDIM, (long)band_px * 512, 0L, 0, band_px, band0, nullptr);
  }
}

// Round 20
// 746.983 us; speedup vs baseline: 1.0320x; 1.0320x over previous
//
#include <hip/hip_runtime.h>
#include <hip/hip_bf16.h>

typedef unsigned short u16;
typedef __attribute__((ext_vector_type(8))) short short8;
typedef __attribute__((ext_vector_type(8))) unsigned short ushort8v;
typedef __attribute__((ext_vector_type(4))) float f32x4;

#define NPIX  65536
#define HH    256
#define WW    256
#define BATCH 2
#define CDIM  192
#define NHEADS 4
#define HD    48
#define OQKV  576
#define HIDN  510
#define OPAD  1024
#define NSLOT 32

// ---------- helpers ----------
__device__ __forceinline__ float bf2f(u16 b) {
  union { unsigned u; float f; } v; v.u = ((unsigned)b) << 16; return v.f;
}
__device__ __forceinline__ u16 f2bf(float f) {
  __bf16 h = (__bf16)f;
  u16 r; __builtin_memcpy(&r, &h, 2); return r;
}
__device__ __forceinline__ void atomAddF(float* p, float v) { unsafeAtomicAdd(p, v); }
__device__ __forceinline__ void gload16(const void* g, void* l) {
  __builtin_amdgcn_global_load_lds((const __attribute__((address_space(1))) unsigned int*)g,
                                   (__attribute__((address_space(3))) unsigned int*)l, 16, 0, 0);
}
// XCD-bijective swizzle (m204): blocks sharing data land on the same XCD's L2.
__device__ __forceinline__ void xcdswz(int& bx, int& by) {
  const int nx = gridDim.x;
  const int tot = nx * gridDim.y;
  const int lin = by * nx + bx;
  const int q = tot >> 3, r = tot & 7;
  const int xcd = lin & 7, pos = lin >> 3;
  const int nl = (xcd < r) ? (xcd * (q + 1) + pos) : (r * (q + 1) + (xcd - r) * q + pos);
  bx = nl % nx; by = nl / nx;
}
// 3-tap row conv on 8 consecutive px starting at col jm (row base rp). 1 vec + 2 scalar loads.
__device__ __forceinline__ void dw3row(const u16* __restrict__ rp, int jm, bool hasL, bool hasR,
                                       float w0, float w1, float w2, float* acc) {
  ushort8v m = *(const ushort8v*)(rp + jm);
  float f[10];
  f[0] = hasL ? bf2f(rp[jm - 1]) : 0.f;
  #pragma unroll
  for (int t = 0; t < 8; ++t) f[t + 1] = bf2f(m[t]);
  f[9] = hasR ? bf2f(rp[jm + 8]) : 0.f;
  #pragma unroll
  for (int i = 0; i < 8; ++i) acc[i] += w0 * f[i] + w1 * f[i + 1] + w2 * f[i + 2];
}

// ---------- ws layout (bytes) ----------
#define OFF_STATS1 ((size_t)0)                       // f32 [32][2][2] = 512
#define OFF_STATS2 ((size_t)512)                     // f32 [32][2][2] = 512
#define OFF_G      ((size_t)1024)                    // f32 [32][2][4][48][48] = 2,359,296
#define OFF_NQ     (OFF_G + 2359296)                 // f32 [32][2][4][48] = 49,152
#define OFF_NK     (OFF_NQ + 49152)                  // 49,152
#define ZERO_BYTES (OFF_NK + 49152)                  // 2,458,624 zeroed each launch
#define OFF_BQ     ZERO_BYTES                        // f32 [2][576] = 4608
#define OFF_B2     (OFF_BQ + 4608)                   // f32 [2][1024] = 8192
#define OFF_M      (OFF_B2 + 8192)                   // bf16 preswz [2][192][192] (reserve 294912)
#define OFF_WQ     (OFF_M + 294912)                  // bf16 [2][576][192] preswz
#define OFF_W2B    (OFF_WQ + 442368)                 // bf16 [2][1024][192] preswz
#define OFF_W3     (OFF_W2B + 786432)                // bf16 [192][512] preswz
#define OFF_T      (OFF_W3 + 196608)                 // bf16 xT [2][65536][192] (stays live)
#define OFF_QKV    (OFF_T + 50331648)                // bf16 planar qkv; q-slice->vdwT, k-slice->x2T
#define OFF_BAND   (OFF_QKV + 150994944)             // hpre band + ygT band

// ---------- 1. fused LN1 stats + transpose: f32 planar -> bf16 T preswz ----------
__global__ __launch_bounds__(256) void k_statsT(const float* __restrict__ P, u16* __restrict__ T,
                                                float* __restrict__ stats) {
  __shared__ u16 ld[128][200];
  const int b = blockIdx.y, n0 = blockIdx.x * 128, tid = threadIdx.x;
  const int slot = blockIdx.x & (NSLOT - 1);
  const float* Pb = P + (((size_t)b * CDIM) << 16) + n0;
  float s = 0.f, ss = 0.f;
  for (int it = 0; it < 24; ++it) {
    int idx = it * 256 + tid;           // 6144 float4: c(192) x j(32)
    int c = idx >> 5, j = idx & 31;
    float4 v = *(const float4*)(Pb + ((size_t)c << 16) + j * 4);
    s  += v.x + v.y + v.z + v.w;
    ss += v.x*v.x + v.y*v.y + v.z*v.z + v.w*v.w;
    int px = j * 4;
    ld[px][c] = f2bf(v.x); ld[px+1][c] = f2bf(v.y);
    ld[px+2][c] = f2bf(v.z); ld[px+3][c] = f2bf(v.w);
  }
  for (int off = 32; off; off >>= 1) { s += __shfl_down(s, off); ss += __shfl_down(ss, off); }
  __shared__ float ls[4], lss[4];
  const int wid = tid >> 6, lane = tid & 63;
  if (lane == 0) { ls[wid] = s; lss[wid] = ss; }
  __syncthreads();
  if (tid == 0) {
    atomAddF(&stats[(slot * BATCH + b) * 2 + 0], ls[0]+ls[1]+ls[2]+ls[3]);
    atomAddF(&stats[(slot * BATCH + b) * 2 + 1], lss[0]+lss[1]+lss[2]+lss[3]);
  }
  u16* Tb = T + (size_t)(b * NPIX + n0) * CDIM;
  for (int it = 0; it < 12; ++it) {
    int idx = it * 256 + tid;
    int ch = idx % 24, nl = idx / 24;
    union { u16 s[8]; uint4 v; } t;
    #pragma unroll
    for (int r = 0; r < 8; ++r) t.s[r] = ld[nl][ch * 8 + r];
    int sch = ch ^ (nl & 7);
    *(uint4*)((char*)(Tb + (size_t)nl * CDIM) + sch * 16) = t.v;
  }
}

// ---------- 2. fold LN into 1x1 weights -> bf16 preswz (key o&7) ----------
__global__ void k_fold(const float* __restrict__ w_in, const float* __restrict__ ln_w,
                       const float* __restrict__ ln_b, const float* __restrict__ stats,
                       u16* __restrict__ W, float* __restrict__ bias, int O_real) {
  const int o = blockIdx.x, b = blockIdx.y, c = threadIdx.x;
  const int Mtot = gridDim.x;
  const float n = (float)(CDIM * NPIX);
  float sum = 0.f, sumsq = 0.f;
  for (int sl = 0; sl < NSLOT; ++sl) {
    sum   += stats[(sl * BATCH + b) * 2 + 0];
    sumsq += stats[(sl * BATCH + b) * 2 + 1];
  }
  const float mean = sum / n;
  const float var = (sumsq - sum * sum / n) / (n - 1.f);
  const float inv = 1.f / (sqrtf(var) + 1e-6f);
  float we = 0.f, cb = 0.f;
  if (o < O_real) {
    float wi = w_in[o * CDIM + c];
    float a  = ln_w[c] * inv;
    we = wi * a;
    cb = wi * (ln_b[c] - mean * a);
  }
  int sch = (c >> 3) ^ (o & 7);
  W[((size_t)b * Mtot + o) * CDIM + sch * 8 + (c & 7)] = f2bf(we);
  for (int off = 32; off; off >>= 1) cb += __shfl_down(cb, off);
  __shared__ float l[3];
  if ((threadIdx.x & 63) == 0) l[threadIdx.x >> 6] = cb;
  __syncthreads();
  if (threadIdx.x == 0) bias[b * Mtot + o] = l[0] + l[1] + l[2];
}

// ---------- 2b. ff_out weights -> bf16 [192][512] preswz ----------
__global__ void k_fold3(const float* __restrict__ w, u16* __restrict__ W3) {
  const int o = blockIdx.x;
  for (int it = 0; it < 2; ++it) {
    int c = it * 256 + threadIdx.x;
    float v = (c < HIDN) ? w[o * HIDN + c] : 0.f;
    int sch = (c >> 3) ^ (o & 7);
    W3[o * 512 + sch * 8 + (c & 7)] = f2bf(v);
  }
}

// ---------- 4. MFMA GEMM: out[b,o,n] = sum_c A[b,o,c]*B[b,n,c] ----------
// KC multiple of 64 (XOR-swizzle closure). NT = n-tile (128 or 256; EPI!=0 requires 128).
// EPI=0: bf16 planar out + bias, stores staged via LDS -> uint4 (coalesced).
// EPI=2: x2 mode -- resid from swizzled bf16 rT, write ONLY swizzled bf16 tout; STATS opt.
// EPI=3: final mode -- resid from swizzled bf16 rT, f32 out staged via LDS -> float4.
template <int KTOT, int KC, int EPI, int STATS, int NT>
__global__ __launch_bounds__(256) void k_mgemm(
    const u16* __restrict__ Bm, const u16* __restrict__ Am,
    const float* __restrict__ bias,
    const u16* __restrict__ rT, long rTbstr,
    void* __restrict__ outv, long Obstr, int out_nstr,
    u16* __restrict__ tout, long toutbstr,
    int Mtot, long Bbstr, long Abstr,
    int nB_base, int nB_rows, int nO_base, float* __restrict__ stats)
{
  constexpr int RBC = KC * 2;
  constexpr int NFR = NT / 64;          // n-fragments per wave
  constexpr int LDSB = (NT + 64) * KC * 2;
  constexpr int EPIB = (EPI == 0) ? 64 * (NT + 8) * 2
                     : (EPI == 2) ? 128 * 66 * 4
                     : ((EPI == 3) ? 64 * 132 * 4 : 0);
  constexpr int TOT  = LDSB > EPIB ? LDSB : EPIB;
  __shared__ char lds[TOT];
  u16* lB = (u16*)lds;
  u16* lA = (u16*)(lds + NT * KC * 2);
  const int b = blockIdx.z;
  int bx = blockIdx.x, by = blockIdx.y;
  xcdswz(bx, by);
  const int o0 = bx * 64;
  const int nB = nB_base + by * NT;
  const int nO = nO_base + by * NT;
  const int tid = threadIdx.x;
  const int lane = tid & 63;
  const int wid = tid >> 6;

  if (EPI == 0 && (nB < 0 || nB >= nB_rows)) {
    u16* op = (u16*)outv;
    uint4 z; z.x = z.y = z.z = z.w = 0u;
    constexpr int CH8 = NT / 8;
    #pragma unroll
    for (int it = 0; it < NT / 32; ++it) {
      int idx = it * 256 + tid;
      int orow = idx / CH8, c8 = idx % CH8;
      *(uint4*)(op + (size_t)b * Obstr + (size_t)(o0 + orow) * out_nstr + nO + c8 * 8) = z;
    }
    return;
  }

  const u16* Bb = Bm + (size_t)b * Bbstr + (size_t)nB * KTOT;
  const u16* Ab = Am + (size_t)b * Abstr + (size_t)o0 * KTOT;

  f32x4 acc[4][NFR];
  #pragma unroll
  for (int m = 0; m < 4; ++m)
    #pragma unroll
    for (int nf = 0; nf < NFR; ++nf) acc[m][nf] = (f32x4){0.f, 0.f, 0.f, 0.f};

  for (int kc0 = 0; kc0 < KTOT; kc0 += KC) {
    if (kc0) __syncthreads();
    constexpr int NCH = KC / 8;
    #pragma unroll
    for (int it = 0; it < NT * NCH / 256; ++it) {
      int idx = it * 256 + tid; int r = idx / NCH, ch = idx % NCH;
      gload16((const char*)(Bb + (size_t)r * KTOT + kc0) + ch * 16, (char*)lB + idx * 16);
    }
    #pragma unroll
    for (int it = 0; it < 64 * NCH / 256; ++it) {
      int idx = it * 256 + tid; int r = idx / NCH, ch = idx % NCH;
      gload16((const char*)(Ab + (size_t)r * KTOT + kc0) + ch * 16, (char*)lA + idx * 16);
    }
    __syncthreads();
    const int lr = lane & 15, g = lane >> 4;
    #pragma unroll
    for (int ks = 0; ks < KC / 32; ++ks) {
      const int ck = ks * 4 + g;
      short8 afr[4], bfr[NFR];
      #pragma unroll
      for (int m = 0; m < 4; ++m) {
        int row = m * 16 + lr;
        afr[m] = *(const short8*)((const char*)lA + row * RBC + ((ck ^ (row & 7)) << 4));
      }
      #pragma unroll
      for (int nf = 0; nf < NFR; ++nf) {
        int row = wid * (NT / 4) + nf * 16 + lr;
        bfr[nf] = *(const short8*)((const char*)lB + row * RBC + ((ck ^ (row & 7)) << 4));
      }
      #pragma unroll
      for (int m = 0; m < 4; ++m)
        #pragma unroll
        for (int nf = 0; nf < NFR; ++nf)
          acc[m][nf] = __builtin_amdgcn_mfma_f32_16x16x32_bf16(afr[m], bfr[nf], acc[m][nf], 0, 0, 0);
    }
  }

  const int col = lane & 15, rg = lane >> 4;
  if constexpr (EPI == 0) {
    constexpr int NTP = NT + 8;
    u16* lst = (u16*)lds;
    __syncthreads();
    #pragma unroll
    for (int m = 0; m < 4; ++m)
      #pragma unroll
      for (int j = 0; j < 4; ++j) {
        int r = m * 16 + rg * 4 + j;
        float bv = bias[b * Mtot + o0 + r];
        #pragma unroll
        for (int nf = 0; nf < NFR; ++nf) {
          int nn = wid * (NT / 4) + nf * 16 + col;
          lst[r * NTP + nn] = f2bf(acc[m][nf][j] + bv);
        }
      }
    __syncthreads();
    u16* op = (u16*)outv;
    constexpr int CH8 = NT / 8;
    #pragma unroll
    for (int it = 0; it < 64 * CH8 / 256; ++it) {
      int idx = it * 256 + tid;
      int r = idx / CH8, ch = idx % CH8;
      uint4 v = *(const uint4*)(lst + r * NTP + ch * 8);
      *(uint4*)(op + (size_t)b * Obstr + (size_t)(o0 + r) * out_nstr + nO + ch * 8) = v;
    }
  } else if constexpr (EPI == 2) {
    // stage acc f32 into lds; then read swizzled rT, add, write swizzled tout only
    float* lBf = (float*)lds;
    __syncthreads();
    #pragma unroll
    for (int m = 0; m < 4; ++m)
      #pragma unroll
      for (int nf = 0; nf < NFR; ++nf)
        #pragma unroll
        for (int j = 0; j < 4; ++j)
          lBf[(wid * 32 + nf * 16 + col) * 66 + m * 16 + rg * 4 + j] = acc[m][nf][j];
    __syncthreads();
    float s = 0.f, ss = 0.f;
    for (int it = 0; it < 4; ++it) {
      int idx = it * 256 + tid;       // 1024 = 128 n x 8 chunks
      int n = idx >> 3, ch3 = idx & 7;
      size_t rowoff = (size_t)(nO + n) * CDIM;
      int chunk = (o0 >> 3) + (ch3 ^ (n & 7));
      uint4 xv = *(const uint4*)((const char*)(rT + (size_t)b * rTbstr + rowoff) + chunk * 16);
      u16* xs = (u16*)&xv;
      union { u16 s[8]; uint4 v; } t;
      #pragma unroll
      for (int r = 0; r < 8; ++r) {
        float rv = bf2f(xs[r]) + lBf[n * 66 + ch3 * 8 + r];
        t.s[r] = f2bf(rv);
        if constexpr (STATS) { s += rv; ss += rv * rv; }
      }
      *(uint4*)((char*)(tout + (size_t)b * toutbstr + rowoff) + chunk * 16) = t.v;
    }
    if constexpr (STATS) {
      for (int off = 32; off; off >>= 1) { s += __shfl_down(s, off); ss += __shfl_down(ss, off); }
      __shared__ float sr1[4], sr2[4];
      if (lane == 0) { sr1[wid] = s; sr2[wid] = ss; }
      __syncthreads();
      if (tid == 0) {
        int slot = by & (NSLOT - 1);
        atomAddF(&stats[(slot * BATCH + b) * 2 + 0], sr1[0]+sr1[1]+sr1[2]+sr1[3]);
        atomAddF(&stats[(slot * BATCH + b) * 2 + 1], sr2[0]+sr2[1]+sr2[2]+sr2[3]);
      }
    }
  } else {   // EPI == 3: add rT (x2T) into acc, stage f32 via LDS, write float4 planar
    u16* lAx = (u16*)lds;
    __syncthreads();
    for (int it = 0; it < 4; ++it) {
      int idx = it * 256 + tid;
      int n = idx >> 3, ch3 = idx & 7;
      int chunk = (o0 >> 3) + (ch3 ^ (n & 7));
      uint4 xv = *(const uint4*)((const char*)(rT + (size_t)b * rTbstr + (size_t)(nO + n) * CDIM) + chunk * 16);
      u16* xs = (u16*)&xv;
      #pragma unroll
      for (int r = 0; r < 8; ++r) lAx[n * 66 + ch3 * 8 + r] = xs[r];
    }
    __syncthreads();
    #pragma unroll
    for (int m = 0; m < 4; ++m)
      #pragma unroll
      for (int nf = 0; nf < NFR; ++nf)
        #pragma unroll
        for (int j = 0; j < 4; ++j) {
          int nl = wid * 32 + nf * 16 + col;
          acc[m][nf][j] += bf2f(lAx[nl * 66 + m * 16 + rg * 4 + j]);
        }
    __syncthreads();
    float* lstf = (float*)lds;
    #pragma unroll
    for (int m = 0; m < 4; ++m)
      #pragma unroll
      for (int nf = 0; nf < NFR; ++nf)
        #pragma unroll
        for (int j = 0; j < 4; ++j)
          lstf[(m * 16 + rg * 4 + j) * 132 + wid * 32 + nf * 16 + col] = acc[m][nf][j];
    __syncthreads();
    float* of = (float*)outv;
    #pragma unroll
    for (int it = 0; it < 8; ++it) {
      int idx = it * 256 + tid;       // 2048 = 64 o x 32 float4
      int r = idx >> 5, q4 = idx & 31;
      float4 v = *(const float4*)&lstf[r * 132 + q4 * 4];
      *(float4*)(of + (size_t)b * Obstr + (size_t)(o0 + r) * out_nstr + nO + q4 * 4) = v;
    }
  }
}

// ---------- 5. fused dw + Gram(MFMA) + L2 norms, 128-px half-row per block ----------
// Stride-128 LDS with XOR chunk swizzle (write j^(c&7), read ck^(row&7)).
__global__ __launch_bounds__(256) void k_gram(const u16* __restrict__ qkv,
                                              const float* __restrict__ dww,
                                              float* __restrict__ G,
                                              float* __restrict__ nq,
                                              float* __restrict__ nk) {
  __shared__ u16 qs[HD][128], ks2[HD][128];
  __shared__ u16 wq[HD][9], wk[HD][9];
  __shared__ float nql[HD], nkl[HD];
  int bx = blockIdx.x, by = blockIdx.y;
  xcdswz(bx, by);
  const int b = by >> 2, h = by & 3;
  const int row = bx >> 1, col0 = (bx & 1) * 128;
  const int slot = bx & (NSLOT - 1);
  const int bh = b * NHEADS + h;
  const int tid = threadIdx.x;

  for (int idx = tid; idx < HD * 9; idx += 256) {
    int c = idx / 9, k9 = idx % 9;
    wq[c][k9] = f2bf(dww[(h * HD + c) * 9 + k9]);
    wk[c][k9] = f2bf(dww[(CDIM + h * HD + c) * 9 + k9]);
  }
  __syncthreads();

  // phase 1: 1536 items = j(16) x c(48) x qk(2); each item: 8 px dw conv
  #pragma unroll 2
  for (int it = 0; it < 6; ++it) {
    int idx = it * 256 + tid;
    int j = idx & 15, cz = idx >> 4;
    int c = cz % HD, qk = cz / HD;
    const u16* base = qkv + (((size_t)(b * OQKV + qk * CDIM + h * HD + c)) << 16);
    const u16* w = qk ? wk[c] : wq[c];
    float acc[8] = {0.f,0.f,0.f,0.f,0.f,0.f,0.f,0.f};
    const int jm = col0 + j * 8;
    const bool hasL = jm > 0, hasR = jm < 248;
    if (row > 0)   dw3row(base + (row - 1) * 256, jm, hasL, hasR, bf2f(w[0]), bf2f(w[1]), bf2f(w[2]), acc);
                   dw3row(base + row * 256,       jm, hasL, hasR, bf2f(w[3]), bf2f(w[4]), bf2f(w[5]), acc);
    if (row < 255) dw3row(base + (row + 1) * 256, jm, hasL, hasR, bf2f(w[6]), bf2f(w[7]), bf2f(w[8]), acc);
    union { u16 s[8]; ushort8v v; } rv;
    float sqs = 0.f;
    #pragma unroll
    for (int i = 0; i < 8; ++i) {
      rv.s[i] = f2bf(acc[i]);
      sqs += acc[i] * acc[i];
    }
    const int sw = (j ^ (c & 7)) * 8;
    if (qk) *(ushort8v*)&ks2[c][sw] = rv.v;
    else    *(ushort8v*)&qs[c][sw]  = rv.v;
    // 16-lane group reduce: all lanes in a group share (c,qk); each (c,qk) occurs once
    sqs += __shfl_down(sqs, 8);
    sqs += __shfl_down(sqs, 4);
    sqs += __shfl_down(sqs, 2);
    sqs += __shfl_down(sqs, 1);
    if ((tid & 15) == 0) { if (qk) nkl[c] = sqs; else nql[c] = sqs; }
  }
  __syncthreads();

  if (tid < HD) atomAddF(&nq[(slot * 2 * NHEADS + bh) * HD + tid], nql[tid]);
  else if (tid < 2*HD) atomAddF(&nk[(slot * 2 * NHEADS + bh) * HD + tid - HD], nkl[tid - HD]);

  // phase 2: Gram via MFMA over 128 px; 9 fragment tiles over 4 waves
  const int lane = tid & 63, wid = tid >> 6;
  const int lr = lane & 15, g = lane >> 4;
  float* Gb = G + (size_t)(slot * 2 * NHEADS + bh) * HD * HD;
  for (int t = wid; t < 9; t += 4) {
    const int m = t / 3, nb = t % 3;
    f32x4 a4 = (f32x4){0.f, 0.f, 0.f, 0.f};
    #pragma unroll
    for (int ksi = 0; ksi < 4; ++ksi) {
      int ck = ksi * 4 + g;
      int ra = m * 16 + lr, rb = nb * 16 + lr;
      short8 af = *(const short8*)&qs[ra][(ck ^ (ra & 7)) * 8];
      short8 bf = *(const short8*)&ks2[rb][(ck ^ (rb & 7)) * 8];
      a4 = __builtin_amdgcn_mfma_f32_16x16x32_bf16(af, bf, a4, 0, 0, 0);
    }
    #pragma unroll
    for (int jj = 0; jj < 4; ++jj)
      atomAddF(&Gb[(m * 16 + g * 4 + jj) * HD + nb * 16 + lr], a4[jj]);
  }
}

// ---------- 7. dw conv on V -> transposed preswz bf16 + fused attnM tail blocks ----------
// grid.x = NPIX/64 + NHEADS; bx >= NPIX/64 runs the attention-M path for head bx-NPIX/64.
__global__ __launch_bounds__(256) void k_dwT(const u16* __restrict__ qkv,
                                             const float* __restrict__ dww,
                                             u16* __restrict__ vdwT, long vdwbstr,
                                             const float* __restrict__ G,
                                             const float* __restrict__ nq,
                                             const float* __restrict__ nk,
                                             const float* __restrict__ temp,
                                             const float* __restrict__ proj_w,
                                             u16* __restrict__ Mb16) {
  __shared__ u16 ld[64][201];
  __shared__ float w9[CDIM][9];
  int bx = blockIdx.x, by = blockIdx.y;
  xcdswz(bx, by);
  const int b = by;
  const int tid = threadIdx.x;

  if (bx >= NPIX / 64) {
    // ---- attnM path (one block per head) ----
    const int h = bx - NPIX / 64;
    const int bh = b * NHEADS + h;
    float* atp = (float*)ld;            // 48*48 f32 = 9216 B (<= ld size)
    float* nqs = (float*)w9;            // 48 f32
    float* nks = nqs + 64;              // 48 f32
    if (tid < HD) {
      float s = 0.f;
      for (int sl = 0; sl < NSLOT; ++sl) s += nq[(sl * 2 * NHEADS + bh) * HD + tid];
      nqs[tid] = fmaxf(sqrtf(s), 1e-12f);
    } else if (tid >= 64 && tid < 64 + HD) {
      int c = tid - 64;
      float s = 0.f;
      for (int sl = 0; sl < NSLOT; ++sl) s += nk[(sl * 2 * NHEADS + bh) * HD + c];
      nks[c] = fmaxf(sqrtf(s), 1e-12f);
    }
    __syncthreads();
    const float t = temp[h];
    for (int idx = tid; idx < HD * HD; idx += 256) {
      int c = idx / HD, d = idx % HD;
      float g = 0.f;
      for (int sl = 0; sl < NSLOT; ++sl)
        g += G[(size_t)(sl * 2 * NHEADS + bh) * HD * HD + idx];
      atp[idx] = g / (nqs[c] * nks[d]) * t;
    }
    __syncthreads();
    if (tid < HD) {
      float m = -1e30f;
      for (int d = 0; d < HD; ++d) m = fmaxf(m, atp[tid * HD + d]);
      float s = 0.f;
      for (int d = 0; d < HD; ++d) { float e = __expf(atp[tid * HD + d] - m); atp[tid * HD + d] = e; s += e; }
      float inv = 1.f / s;
      for (int d = 0; d < HD; ++d) atp[tid * HD + d] *= inv;
    }
    __syncthreads();
    for (int idx = tid; idx < CDIM * HD; idx += 256) {
      int o = idx / HD, d = idx % HD;
      float acc = 0.f;
      for (int c = 0; c < HD; ++c) acc += proj_w[o * CDIM + h * HD + c] * atp[c * HD + d];
      int cf = h * HD + d;
      int sch = (cf >> 3) ^ (o & 7);
      Mb16[((size_t)(b * CDIM + o)) * CDIM + sch * 8 + (cf & 7)] = f2bf(acc);
    }
    return;
  }

  // ---- dw(V) path ----
  const int p0 = bx * 64;
  const int row = p0 >> 8, col0 = p0 & 255;
  for (int idx = tid; idx < CDIM * 9; idx += 256) w9[idx / 9][idx % 9] = dww[384 * 9 + idx];
  __syncthreads();
  #pragma unroll 2
  for (int it = 0; it < 6; ++it) {
    int idx = it * 256 + tid;          // 1536 items: j(8) x c(192)
    int j = idx & 7, c = idx >> 3;
    const u16* base = qkv + (((size_t)(b * OQKV + 384 + c)) << 16);
    const float* w = w9[c];
    float acc[8] = {0.f,0.f,0.f,0.f,0.f,0.f,0.f,0.f};
    const int jm = col0 + j * 8;
    const bool hasL = jm > 0, hasR = jm < 248;
    if (row > 0)   dw3row(base + (row - 1) * 256, jm, hasL, hasR, w[0], w[1], w[2], acc);
                   dw3row(base + row * 256,       jm, hasL, hasR, w[3], w[4], w[5], acc);
    if (row < 255) dw3row(base + (row + 1) * 256, jm, hasL, hasR, w[6], w[7], w[8], acc);
    #pragma unroll
    for (int i = 0; i < 8; ++i) ld[j * 8 + i][c] = f2bf(acc[i]);
  }
  __syncthreads();
  u16* Tb = vdwT + (size_t)b * vdwbstr + (size_t)p0 * CDIM;
  for (int it = 0; it < 6; ++it) {
    int idx = it * 256 + tid;          // 1536 = 64 px * 24 chunks
    int ch = idx % 24, pl = idx / 24;
    union { u16 s[8]; uint4 v; } t;
    #pragma unroll
    for (int r = 0; r < 8; ++r) t.s[r] = ld[pl][ch * 8 + r];
    int sch = ch ^ (pl & 7);
    *(uint4*)((char*)(Tb + (size_t)pl * CDIM) + sch * 16) = t.v;
  }
}

// ---------- 8. dw + gelu gate on hpre band -> ygT (1 row, 32 cols per block) ----------
__global__ __launch_bounds__(256) void k_dwgT(const u16* __restrict__ hp_, const float* __restrict__ w9,
                                              u16* __restrict__ ygT, int rows_loc, int band_px) {
  __shared__ u16 ld[32][515];
  int bx = blockIdx.x, by = blockIdx.y;
  xcdswz(bx, by);
  const int b = by;
  const int p0 = bx * 32;
  const int olr = p0 >> 8, col0 = p0 & 255;
  const int tid = threadIdx.x;
  if (tid < 64) {                      // zero pad channels 510,511
    int px = tid >> 1, c = 510 + (tid & 1);
    ld[px][c] = 0;
  }
  __syncthreads();
  #pragma unroll 2
  for (int it = 0; it < 8; ++it) {
    int idx = it * 256 + tid;          // 2040 items: j(4) x c(510)
    if (idx < HIDN * 4) {
      int j = idx & 3, c = idx >> 2;
      const u16* ia = hp_ + (size_t)(b * OPAD + c) * rows_loc * 256;
      const u16* ig = hp_ + (size_t)(b * OPAD + c + HIDN) * rows_loc * 256;
      float aa[8] = {0.f,0.f,0.f,0.f,0.f,0.f,0.f,0.f};
      float gg[8] = {0.f,0.f,0.f,0.f,0.f,0.f,0.f,0.f};
      const int jm = col0 + j * 8;
      const bool hasL = jm > 0, hasR = jm < 248;
      #pragma unroll
      for (int dr = 0; dr < 3; ++dr) {
        dw3row(ia + (olr + dr) * 256, jm, hasL, hasR,
               w9[c * 9 + dr * 3], w9[c * 9 + dr * 3 + 1], w9[c * 9 + dr * 3 + 2], aa);
        dw3row(ig + (olr + dr) * 256, jm, hasL, hasR,
               w9[(c + HIDN) * 9 + dr * 3], w9[(c + HIDN) * 9 + dr * 3 + 1],
               w9[(c + HIDN) * 9 + dr * 3 + 2], gg);
      }
      #pragma unroll
      for (int i = 0; i < 8; ++i) {
        float a = aa[i];
        float gel = 0.5f * a * (1.f + erff(a * 0.70710678118654752f));
        ld[j * 8 + i][c] = f2bf(gel * gg[i]);
      }
    }
  }
  __syncthreads();
  u16* Tb = ygT + ((size_t)b * band_px + p0) * 512;
  for (int it = 0; it < 8; ++it) {
    int idx = it * 256 + tid;          // 2048 = 32 px * 64 chunks
    int ch = idx & 63, pl = idx >> 6;
    union { u16 s[8]; uint4 v; } t;
    #pragma unroll
    for (int r = 0; r < 8; ++r) t.s[r] = ld[pl][ch * 8 + r];
    int sch = ch ^ (pl & 7);
    *(uint4*)((char*)(Tb + (size_t)pl * 512) + sch * 16) = t.v;
  }
}

// ---------- launch ----------
extern "C" void kernel_launch(void* const* d_in, const int* in_sizes, int n_in,
                              void* d_out, int out_size, void* d_ws, size_t ws_size,
                              hipStream_t stream) {
  const float* x       = (const float*)d_in[0];
  const float* n1_w    = (const float*)d_in[1];
  const float* n1_b    = (const float*)d_in[2];
  const float* qkv_w   = (const float*)d_in[3];
  const float* qkv_dw  = (const float*)d_in[4];
  const float* proj_w  = (const float*)d_in[5];
  const float* temp    = (const float*)d_in[6];
  const float* n2_w    = (const float*)d_in[7];
  const float* n2_b    = (const float*)d_in[8];
  const float* ff_in_w = (const float*)d_in[9];
  const float* ff_dw   = (const float*)d_in[10];
  const float* ff_out_w= (const float*)d_in[11];

  char* ws = (char*)d_ws;
  float* stats1 = (float*)(ws + OFF_STATS1);
  float* stats2 = (float*)(ws + OFF_STATS2);
  float* G      = (float*)(ws + OFF_G);
  float* nq     = (float*)(ws + OFF_NQ);
  float* nk     = (float*)(ws + OFF_NK);
  float* biasq  = (float*)(ws + OFF_BQ);
  float* bias2  = (float*)(ws + OFF_B2);
  u16*   Mb16   = (u16*)(ws + OFF_M);
  u16*   Wq     = (u16*)(ws + OFF_WQ);
  u16*   W2b    = (u16*)(ws + OFF_W2B);
  u16*   W3     = (u16*)(ws + OFF_W3);
  u16*   xT     = (u16*)(ws + OFF_T);              // stays live through x2 gemm
  u16*   qkv    = (u16*)(ws + OFF_QKV);            // planar qkv
  u16*   vdwT   = qkv;                             // overlays dead q-slice
  u16*   x2T    = qkv + (size_t)CDIM * NPIX;       // overlays dead k-slice
  const long qkvbstr = (long)OQKV * NPIX;          // batch stride for both overlays
  float* outp   = (float*)d_out;

  int NP = 32;
  const int cand[5] = {1, 2, 4, 8, 16};
  for (int i = 0; i < 5; ++i) {
    int rws = 256 / cand[i], rl = rws + 2;
    size_t band = (size_t)2 * OPAD * rl * 256 * 2 + (size_t)2 * rws * 256 * 512 * 2;
    if (OFF_BAND + band + ((size_t)8 << 20) <= ws_size) { NP = cand[i]; break; }
  }
  const int rows = 256 / NP, rows_loc = rows + 2, band_px = rows * 256;
  u16* hpre = (u16*)(ws + OFF_BAND);
  u16* ygT  = (u16*)(ws + OFF_BAND + (size_t)2 * OPAD * rows_loc * 256 * 2);

  hipMemsetAsync(ws, 0, ZERO_BYTES, stream);

  // ---- attention ----
  k_statsT<<<dim3(NPIX / 128, BATCH), 256, 0, stream>>>(x, xT, stats1);
  k_fold<<<dim3(OQKV, BATCH), CDIM, 0, stream>>>(qkv_w, n1_w, n1_b, stats1, Wq, biasq, OQKV);
  k_mgemm<192, 64, 0, 0, 256><<<dim3(OQKV / 64, NPIX / 256, BATCH), 256, 0, stream>>>(
      xT, Wq, biasq, nullptr, 0L, qkv, (long)OQKV * NPIX, NPIX, nullptr, 0L,
      OQKV, (long)NPIX * CDIM, (long)OQKV * CDIM, 0, NPIX, 0, nullptr);
  k_gram<<<dim3(512, BATCH * NHEADS), 256, 0, stream>>>(qkv, qkv_dw, G, nq, nk);
  // dw(V) + fused attnM tail blocks
  k_dwT<<<dim3(NPIX / 64 + NHEADS, BATCH), 256, 0, stream>>>(
      qkv, qkv_dw, vdwT, qkvbstr, G, nq, nk, temp, proj_w, Mb16);
  // x2 = x + M@dw(V): resid from xT (bf16 swz), write ONLY x2T (bf16 swz) + stats2
  k_mgemm<192, 64, 2, 1, 128><<<dim3(CDIM / 64, NPIX / 128, BATCH), 256, 0, stream>>>(
      vdwT, Mb16, nullptr, xT, (long)NPIX * CDIM, nullptr, 0L, 0, x2T, qkvbstr,
      CDIM, qkvbstr, (long)CDIM * CDIM, 0, NPIX, 0, stats2);

  // ---- GDFN ----
  k_fold<<<dim3(OPAD, BATCH), CDIM, 0, stream>>>(ff_in_w, n2_w, n2_b, stats2, W2b, bias2, 1020);
  k_fold3<<<dim3(CDIM), 256, 0, stream>>>(ff_out_w, W3);
  for (int rp = 0; rp < NP; ++rp) {
    const int band0 = rp * band_px;
    k_mgemm<192, 64, 0, 0, 256><<<dim3(OPAD / 64, rows_loc, BATCH), 256, 0, stream>>>(
        x2T, W2b, bias2, nullptr, 0L, hpre, (long)OPAD * rows_loc * 256, rows_loc * 256,
        nullptr, 0L, OPAD, qkvbstr, (long)OPAD * CDIM, band0 - 256, NPIX, 0, nullptr);
    k_dwgT<<<dim3(band_px / 32, BATCH), 256, 0, stream>>>(hpre, ff_dw, ygT, rows_loc, band_px);
    // out = x2 + ff_out@ygT: resid from x2T, f32 out staged -> float4
    k_mgemm<512, 128, 3, 0, 128><<<dim3(CDIM / 64, rows * 2, BATCH), 256, 0, stream>>>(
        ygT, W3, nullptr, x2T, qkvbstr, outp, (long)CDIM * NPIX, NPIX, nullptr, 0L,
        CDIM, (long)band_px * 512, 0L, 0, band_px, band0, nullptr);
  }
}